// Round 3
// baseline (883.496 us; speedup 1.0000x reference)
//
#include <hip/hip_runtime.h>
#include <hip/hip_bf16.h>
#include <math.h>

#define SUB_NO 20
#define T_NO   200
#define BASIS_NO 19
#define T_DATA 100000
#define E_NO   800
#define I_NO   200

using u16 = unsigned short;
using u32 = unsigned int;
using u64 = unsigned long long;

__device__ __forceinline__ float bf2f(u16 h) {
  return __builtin_bit_cast(float, (u32)h << 16);
}
__device__ __forceinline__ u16 f2bf(float f) {
  u32 u = __builtin_bit_cast(u32, f);
  u += 0x7FFFu + ((u >> 16) & 1u);  // RNE
  return (u16)(u >> 16);
}
// dtype-polymorphic load/store: bf==true -> bf16, else fp32
__device__ __forceinline__ float ldx(const void* p, int i, bool bf) {
  return bf ? bf2f(((const u16*)p)[i]) : ((const float*)p)[i];
}
__device__ __forceinline__ void stx(void* p, int i, float v, bool bf) {
  if (bf) ((u16*)p)[i] = f2bf(v); else ((float*)p)[i] = v;
}

// ---------------------------------------------------------------------------
// K0: cos basis -> conv kernels (fp32 in ws, packed [m][k][4]), hist kernels,
//     out_filters (rows 80000.. of d_out), synapse assignment tables.
// ---------------------------------------------------------------------------
__global__ __launch_bounds__(256) void k0_prep(
    const u32* __restrict__ probe,  // C_den dword0: 0 -> fp32, else bf16
    const void* __restrict__ Wns, const void* __restrict__ Ws,
    const void* __restrict__ hsw, const void* __restrict__ hnsw,
    const void* __restrict__ Cse, const void* __restrict__ Csi,
    float* __restrict__ kern4, float* __restrict__ hist_s,
    float* __restrict__ hist_ns, int* __restrict__ ae, int* __restrict__ ai,
    void* __restrict__ out) {
  const bool bf = (probe[0] != 0u);
  __shared__ float cb[BASIS_NO * T_NO];
  const int tid = threadIdx.x;
  constexpr float PI = 3.14159265358979323846f;
  for (int idx = tid; idx < BASIS_NO * T_NO; idx += 256) {
    int b = idx / T_NO, j = idx - b * T_NO;
    float phi = 0.5f * PI * (float)b;
    float raw = 5.0f * logf((float)j + 1.0f);
    float v = 0.f;
    if (raw >= phi - PI && raw <= phi + PI) v = 0.5f * cosf(raw - phi) + 0.5f;
    cb[idx] = v;
  }
  __syncthreads();
  const int fbase = 2 * T_DATA;  // out_filters start (element index into d_out)
  for (int idx = tid; idx < SUB_NO * T_NO; idx += 256) {
    int k = idx / T_NO, j = idx - k * T_NO;
    float e_ns = 0.f, i_ns = 0.f, e_s = 0.f, i_s = 0.f;
#pragma unroll
    for (int b = 0; b < BASIS_NO; ++b) {
      float c = cb[b * T_NO + j];
      e_ns = fmaf(ldx(Wns, (k * BASIS_NO + b) * 2 + 0, bf), c, e_ns);
      i_ns = fmaf(ldx(Wns, (k * BASIS_NO + b) * 2 + 1, bf), c, i_ns);
      e_s  = fmaf(ldx(Ws,  (k * BASIS_NO + b) * 2 + 0, bf), c, e_s);
      i_s  = fmaf(ldx(Ws,  (k * BASIS_NO + b) * 2 + 1, bf), c, i_s);
    }
    float* kp = kern4 + (j * SUB_NO + k) * 4;
    kp[0] = e_ns; kp[1] = i_ns; kp[2] = e_s; kp[3] = i_s;
    stx(out, fbase + (0 * SUB_NO + k) * T_NO + j, e_ns, bf);
    stx(out, fbase + (1 * SUB_NO + k) * T_NO + j, i_ns, bf);
    stx(out, fbase + (2 * SUB_NO + k) * T_NO + j, e_s,  bf);
    stx(out, fbase + (3 * SUB_NO + k) * T_NO + j, i_s,  bf);
  }
  for (int j = tid; j < T_NO; j += 256) {
    float hs = 0.f, hns = 0.f;
#pragma unroll
    for (int b = 0; b < BASIS_NO; ++b) {
      float c = cb[b * T_NO + j];
      hs  = fmaf(ldx(hsw,  b, bf), c, hs);
      hns = fmaf(ldx(hnsw, b, bf), c, hns);
    }
    hist_s[j] = hs; hist_ns[j] = hns;
    stx(out, fbase + 80 * T_NO + j, hns, bf);
    stx(out, fbase + 81 * T_NO + j, hs,  bf);
  }
  for (int e = tid; e < E_NO; e += 256) {
    int a = 0;
    for (int k = 0; k < SUB_NO; ++k) if (ldx(Cse, k * E_NO + e, bf) != 0.f) a = k;
    ae[e] = a;
  }
  for (int e = tid; e < I_NO; e += 256) {
    int a = 0;
    for (int k = 0; k < SUB_NO; ++k) if (ldx(Csi, k * I_NO + e, bf) != 0.f) a = k;
    ai[e] = a;
  }
}

// ---------------------------------------------------------------------------
// K2: per 256-timestep block: bin spikes (window of 456 rows) into packed u32
// LDS tile via integer atomics (exact), 4x200-tap causal conv (fp32),
// Z hist conv, tree tanh recursion, sigmoid/tanh epilogue.
// ---------------------------------------------------------------------------
#define K2_BT 256
#define TROWS (K2_BT + T_NO)  // 456

__global__ __launch_bounds__(256) void k2_main(
    const u32* __restrict__ probe,
    const void* __restrict__ Se, const void* __restrict__ Si,
    const float* __restrict__ kern4,
    const float* __restrict__ hist_s, const float* __restrict__ hist_ns,
    const int* __restrict__ ae, const int* __restrict__ ai,
    const void* __restrict__ Z, const void* __restrict__ Wsub_ns,
    const void* __restrict__ Wsub_s, const void* __restrict__ Vo,
    const void* __restrict__ Thns, const void* __restrict__ Ths,
    void* __restrict__ out) {
  const bool bf = (probe[0] != 0u);
  __shared__ u32 tile[TROWS * SUB_NO];  // 456 x 20 packed counts (e | i<<16)
  __shared__ float ztile[TROWS];
  __shared__ int lae[E_NO];
  __shared__ int lai[I_NO];
  __shared__ float ws2_l[SUB_NO], wns2_l[SUB_NO], ths_l[SUB_NO], thns_l[SUB_NO];
  const int tid = threadIdx.x;
  const int t0 = blockIdx.x * K2_BT;

  for (int n = tid; n < TROWS * SUB_NO; n += 256) tile[n] = 0u;
  for (int n = tid; n < E_NO; n += 256) lae[n] = ae[n];
  for (int n = tid; n < I_NO; n += 256) lai[n] = ai[n];
  const int zbase = t0 - T_NO;
  for (int n = tid; n < TROWS; n += 256) {
    int g = zbase + n;
    ztile[n] = (g >= 0 && g < T_DATA) ? ldx(Z, g, bf) : 0.f;
  }
  if (tid < SUB_NO) {
    float w = ldx(Wsub_s, tid, bf);   ws2_l[tid]  = w * w;
    float wn = ldx(Wsub_ns, tid, bf); wns2_l[tid] = wn * wn;
    ths_l[tid]  = ldx(Ths, tid, bf);
    thns_l[tid] = ldx(Thns, tid, bf);
  }
  __syncthreads();

  const int row_lo = max(t0 - T_NO, 0);
  const int row_hi = min(t0 + K2_BT, T_DATA);
  const int nrows = row_hi - row_lo;
  const int lrow0 = row_lo - (t0 - T_NO);  // tile row of global row_lo

  if (bf) {
    {  // E spikes, bf16: 4 per u64
      const u64* p4 = (const u64*)((const u16*)Se + (size_t)row_lo * E_NO);
      const int total = nrows * (E_NO / 4);
      for (int p = tid; p < total; p += 256) {
        u64 u = p4[p];
        if (u) {
          int r = p / (E_NO / 4), e0 = (p - r * (E_NO / 4)) * 4;
          u32* base = &tile[(lrow0 + r) * SUB_NO];
#pragma unroll
          for (int q = 0; q < 4; ++q)
            if ((u16)(u >> (16 * q))) atomicAdd(&base[lae[e0 + q]], 1u);
        }
      }
    }
    {  // I spikes, bf16
      const u64* p4 = (const u64*)((const u16*)Si + (size_t)row_lo * I_NO);
      const int total = nrows * (I_NO / 4);
      for (int p = tid; p < total; p += 256) {
        u64 u = p4[p];
        if (u) {
          int r = p / (I_NO / 4), e0 = (p - r * (I_NO / 4)) * 4;
          u32* base = &tile[(lrow0 + r) * SUB_NO];
#pragma unroll
          for (int q = 0; q < 4; ++q)
            if ((u16)(u >> (16 * q))) atomicAdd(&base[lai[e0 + q]], 0x10000u);
        }
      }
    }
  } else {
    {  // E spikes, fp32: 4 per uint4
      const uint4* p4 = (const uint4*)((const float*)Se + (size_t)row_lo * E_NO);
      const int total = nrows * (E_NO / 4);
      for (int p = tid; p < total; p += 256) {
        uint4 u = p4[p];
        if (u.x | u.y | u.z | u.w) {
          int r = p / (E_NO / 4), e0 = (p - r * (E_NO / 4)) * 4;
          u32* base = &tile[(lrow0 + r) * SUB_NO];
          if (u.x) atomicAdd(&base[lae[e0 + 0]], 1u);
          if (u.y) atomicAdd(&base[lae[e0 + 1]], 1u);
          if (u.z) atomicAdd(&base[lae[e0 + 2]], 1u);
          if (u.w) atomicAdd(&base[lae[e0 + 3]], 1u);
        }
      }
    }
    {  // I spikes, fp32
      const uint4* p4 = (const uint4*)((const float*)Si + (size_t)row_lo * I_NO);
      const int total = nrows * (I_NO / 4);
      for (int p = tid; p < total; p += 256) {
        uint4 u = p4[p];
        if (u.x | u.y | u.z | u.w) {
          int r = p / (I_NO / 4), e0 = (p - r * (I_NO / 4)) * 4;
          u32* base = &tile[(lrow0 + r) * SUB_NO];
          if (u.x) atomicAdd(&base[lai[e0 + 0]], 0x10000u);
          if (u.y) atomicAdd(&base[lai[e0 + 1]], 0x10000u);
          if (u.z) atomicAdd(&base[lai[e0 + 2]], 0x10000u);
          if (u.w) atomicAdd(&base[lai[e0 + 3]], 0x10000u);
        }
      }
    }
  }
  __syncthreads();

  float acc_ns[SUB_NO], acc_s[SUB_NO];
#pragma unroll
  for (int k = 0; k < SUB_NO; ++k) { acc_ns[k] = 0.f; acc_s[k] = 0.f; }
  float h_s = 0.f, h_ns = 0.f;
  const int lt = tid;

#pragma unroll 2
  for (int m = 0; m < T_NO; ++m) {
    const uint4* rp = reinterpret_cast<const uint4*>(&tile[(lt + T_NO - m) * SUB_NO]);
    uint4 q0 = rp[0], q1 = rp[1], q2 = rp[2], q3 = rp[3], q4 = rp[4];
    u32 uu[SUB_NO] = {q0.x, q0.y, q0.z, q0.w, q1.x, q1.y, q1.z, q1.w,
                      q2.x, q2.y, q2.z, q2.w, q3.x, q3.y, q3.z, q3.w,
                      q4.x, q4.y, q4.z, q4.w};
    float zv = ztile[lt + T_NO - 1 - m];
    h_s  = fmaf(hist_s[m],  zv, h_s);
    h_ns = fmaf(hist_ns[m], zv, h_ns);
    const float* kp = kern4 + m * (SUB_NO * 4);
#pragma unroll
    for (int k = 0; k < SUB_NO; ++k) {
      float ev = (float)(uu[k] & 0xFFFFu);  // exact integer counts
      float iv = (float)(uu[k] >> 16);
      acc_ns[k] = fmaf(kp[k * 4 + 0], ev, acc_ns[k]);
      acc_ns[k] = fmaf(kp[k * 4 + 1], iv, acc_ns[k]);
      acc_s[k]  = fmaf(kp[k * 4 + 2], ev, acc_s[k]);
      acc_s[k]  = fmaf(kp[k * 4 + 3], iv, acc_s[k]);
    }
  }

  // tree recursion (binary tree: children of k are 2k+1, 2k+2)
  float so[SUB_NO], no[SUB_NO];
#pragma unroll
  for (int k = SUB_NO - 1; k >= 1; --k) {
    float as_ = acc_s[k] + ths_l[k];
    float an_ = acc_ns[k] + thns_l[k];
    const int c1 = 2 * k + 1, c2 = 2 * k + 2;
    if (c1 < SUB_NO) { as_ += ws2_l[c1] * so[c1]; an_ += wns2_l[c1] * no[c1]; }
    if (c2 < SUB_NO) { as_ += ws2_l[c2] * so[c2]; an_ += wns2_l[c2] * no[c2]; }
    so[k] = tanhf(as_);
    no[k] = tanhf(an_);
  }
  float zs = h_s + acc_s[0] + ths_l[0] + ws2_l[1] * so[1] + ws2_l[2] * so[2];
  float zn = h_ns + acc_ns[0] + thns_l[0] + wns2_l[1] * no[1] + wns2_l[2] * no[2];
  float fZ = 1.f / (1.f + expf(-zs));
  float fV = tanhf(zn) * wns2_l[0] + ldx(Vo, 0, bf);

  const int t = t0 + lt;
  if (t < T_DATA) {
    stx(out, t, fV, bf);            // final_V
    stx(out, T_DATA + t, fZ, bf);   // final_Z
  }
}

// ---------------------------------------------------------------------------
extern "C" void kernel_launch(void* const* d_in, const int* in_sizes, int n_in,
                              void* d_out, int out_size, void* d_ws, size_t ws_size,
                              hipStream_t stream) {
  const void* Se      = d_in[0];
  const void* Si      = d_in[1];
  const void* Z       = d_in[2];
  const u32*  probe   = (const u32*)d_in[3];  // C_den: dword0==0 -> fp32, else bf16
  const void* Cse     = d_in[4];
  const void* Csi     = d_in[5];
  const void* Wns     = d_in[6];
  const void* Ws_     = d_in[7];
  const void* Wsub_ns = d_in[8];
  const void* Wsub_s  = d_in[9];
  const void* Vo      = d_in[10];
  const void* Thns    = d_in[11];
  const void* Ths     = d_in[12];
  const void* hsw     = d_in[13];
  const void* hnsw    = d_in[14];

  float* wsf      = (float*)d_ws;
  float* kern4    = wsf;                      // 16000 f
  float* hist_s   = wsf + 16000;              // 200 f
  float* hist_ns  = wsf + 16200;              // 200 f
  int*   ae       = (int*)(wsf + 16400);      // 800 i
  int*   ai       = (int*)(wsf + 17200);      // 200 i  -> 69.6 KB total

  hipLaunchKernelGGL(k0_prep, dim3(1), dim3(256), 0, stream,
                     probe, Wns, Ws_, hsw, hnsw, Cse, Csi,
                     kern4, hist_s, hist_ns, ae, ai, d_out);
  hipLaunchKernelGGL(k2_main, dim3((T_DATA + K2_BT - 1) / K2_BT), dim3(256), 0, stream,
                     probe, Se, Si, kern4, hist_s, hist_ns, ae, ai, Z,
                     Wsub_ns, Wsub_s, Vo, Thns, Ths, d_out);
}

// Round 4
// 696.246 us; speedup vs baseline: 1.2689x; 1.2689x over previous
//
#include <hip/hip_runtime.h>
#include <hip/hip_bf16.h>
#include <math.h>

#define SUB_NO 20
#define T_NO   200
#define BASIS_NO 19
#define T_DATA 100000
#define E_NO   800
#define I_NO   200

using u16 = unsigned short;
using u32 = unsigned int;
using u64 = unsigned long long;

__device__ __forceinline__ float bf2f(u16 h) {
  return __builtin_bit_cast(float, (u32)h << 16);
}
__device__ __forceinline__ u16 f2bf(float f) {
  u32 u = __builtin_bit_cast(u32, f);
  u += 0x7FFFu + ((u >> 16) & 1u);  // RNE
  return (u16)(u >> 16);
}
// dtype-polymorphic load/store: bf==true -> bf16, else fp32
__device__ __forceinline__ float ldx(const void* p, int i, bool bf) {
  return bf ? bf2f(((const u16*)p)[i]) : ((const float*)p)[i];
}
__device__ __forceinline__ void stx(void* p, int i, float v, bool bf) {
  if (bf) ((u16*)p)[i] = f2bf(v); else ((float*)p)[i] = v;
}

// ---------------------------------------------------------------------------
// K0: multi-block. cos basis (per-block LDS) -> conv kernels (fp32 ws,
// [m][k][4]), hist kernels, out_filters, assignment tables.
// Work items: [0,4000) kern, [4000,4200) hist, [4200,5000) ae, [5000,5200) ai.
// ---------------------------------------------------------------------------
#define K0_BLOCKS 21
__global__ __launch_bounds__(256) void k0_prep(
    const u32* __restrict__ probe,  // C_den dword0: 0 -> fp32, else bf16
    const void* __restrict__ Wns, const void* __restrict__ Ws,
    const void* __restrict__ hsw, const void* __restrict__ hnsw,
    const void* __restrict__ Cse, const void* __restrict__ Csi,
    float* __restrict__ kern4, float* __restrict__ hist_s,
    float* __restrict__ hist_ns, int* __restrict__ ae, int* __restrict__ ai,
    void* __restrict__ out) {
  const bool bf = (probe[0] != 0u);
  __shared__ float cb[BASIS_NO * T_NO];
  const int tid = threadIdx.x;
  constexpr float PI = 3.14159265358979323846f;
  for (int idx = tid; idx < BASIS_NO * T_NO; idx += 256) {
    int b = idx / T_NO, j = idx - b * T_NO;
    float phi = 0.5f * PI * (float)b;
    float raw = 5.0f * logf((float)j + 1.0f);
    float v = 0.f;
    if (raw >= phi - PI && raw <= phi + PI) v = 0.5f * cosf(raw - phi) + 0.5f;
    cb[idx] = v;
  }
  __syncthreads();
  const int fbase = 2 * T_DATA;  // out_filters start in d_out
  for (int gid = blockIdx.x * 256 + tid; gid < 5200; gid += K0_BLOCKS * 256) {
    if (gid < 4000) {
      int k = gid / T_NO, j = gid - k * T_NO;
      float e_ns = 0.f, i_ns = 0.f, e_s = 0.f, i_s = 0.f;
#pragma unroll
      for (int b = 0; b < BASIS_NO; ++b) {
        float c = cb[b * T_NO + j];
        e_ns = fmaf(ldx(Wns, (k * BASIS_NO + b) * 2 + 0, bf), c, e_ns);
        i_ns = fmaf(ldx(Wns, (k * BASIS_NO + b) * 2 + 1, bf), c, i_ns);
        e_s  = fmaf(ldx(Ws,  (k * BASIS_NO + b) * 2 + 0, bf), c, e_s);
        i_s  = fmaf(ldx(Ws,  (k * BASIS_NO + b) * 2 + 1, bf), c, i_s);
      }
      float* kp = kern4 + (j * SUB_NO + k) * 4;
      kp[0] = e_ns; kp[1] = i_ns; kp[2] = e_s; kp[3] = i_s;
      stx(out, fbase + (0 * SUB_NO + k) * T_NO + j, e_ns, bf);
      stx(out, fbase + (1 * SUB_NO + k) * T_NO + j, i_ns, bf);
      stx(out, fbase + (2 * SUB_NO + k) * T_NO + j, e_s,  bf);
      stx(out, fbase + (3 * SUB_NO + k) * T_NO + j, i_s,  bf);
    } else if (gid < 4200) {
      int j = gid - 4000;
      float hs = 0.f, hns = 0.f;
#pragma unroll
      for (int b = 0; b < BASIS_NO; ++b) {
        float c = cb[b * T_NO + j];
        hs  = fmaf(ldx(hsw,  b, bf), c, hs);
        hns = fmaf(ldx(hnsw, b, bf), c, hns);
      }
      hist_s[j] = hs; hist_ns[j] = hns;
      stx(out, fbase + 80 * T_NO + j, hns, bf);
      stx(out, fbase + 81 * T_NO + j, hs,  bf);
    } else if (gid < 5000) {
      int e = gid - 4200;
      int a = 0;
      for (int k = 0; k < SUB_NO; ++k) if (ldx(Cse, k * E_NO + e, bf) != 0.f) a = k;
      ae[e] = a;
    } else {
      int e = gid - 5000;
      int a = 0;
      for (int k = 0; k < SUB_NO; ++k) if (ldx(Csi, k * I_NO + e, bf) != 0.f) a = k;
      ai[e] = a;
    }
  }
}

// ---------------------------------------------------------------------------
// K1: stream spikes once (no halo), bin into packed u32 counts (e | i<<16)
// via integer LDS atomics (exact), write syn_pair[t][k] to ws.
// ---------------------------------------------------------------------------
#define K1_BT 128
__global__ __launch_bounds__(256) void k1_agg(
    const u32* __restrict__ probe,
    const void* __restrict__ Se, const void* __restrict__ Si,
    const int* __restrict__ ae, const int* __restrict__ ai,
    u32* __restrict__ syn_pair) {
  const bool bf = (probe[0] != 0u);
  __shared__ u32 bins[K1_BT * SUB_NO];
  __shared__ int lae[E_NO];
  __shared__ int lai[I_NO];
  const int tid = threadIdx.x;
  const int t0 = blockIdx.x * K1_BT;
  const int nt = min(K1_BT, T_DATA - t0);
  for (int n = tid; n < K1_BT * SUB_NO; n += 256) bins[n] = 0u;
  for (int n = tid; n < E_NO; n += 256) lae[n] = ae[n];
  for (int n = tid; n < I_NO; n += 256) lai[n] = ai[n];
  __syncthreads();

  if (bf) {
    {  // E: 8 bf16 per uint4, 100 uint4/row
      const uint4* p = (const uint4*)((const u16*)Se + (size_t)t0 * E_NO);
      const int wpr = E_NO / 8, total = nt * wpr;
      for (int w = tid; w < total; w += 256) {
        uint4 v = p[w];
        u64 a = ((u64)v.y << 32) | v.x;
        u64 b = ((u64)v.w << 32) | v.z;
        if (a | b) {
          int r = w / wpr, e0 = (w - r * wpr) * 8;
          u32* bb = &bins[r * SUB_NO];
#pragma unroll
          for (int q = 0; q < 4; ++q)
            if ((u16)(a >> (16 * q))) atomicAdd(&bb[lae[e0 + q]], 1u);
#pragma unroll
          for (int q = 0; q < 4; ++q)
            if ((u16)(b >> (16 * q))) atomicAdd(&bb[lae[e0 + 4 + q]], 1u);
        }
      }
    }
    {  // I
      const uint4* p = (const uint4*)((const u16*)Si + (size_t)t0 * I_NO);
      const int wpr = I_NO / 8, total = nt * wpr;
      for (int w = tid; w < total; w += 256) {
        uint4 v = p[w];
        u64 a = ((u64)v.y << 32) | v.x;
        u64 b = ((u64)v.w << 32) | v.z;
        if (a | b) {
          int r = w / wpr, e0 = (w - r * wpr) * 8;
          u32* bb = &bins[r * SUB_NO];
#pragma unroll
          for (int q = 0; q < 4; ++q)
            if ((u16)(a >> (16 * q))) atomicAdd(&bb[lai[e0 + q]], 0x10000u);
#pragma unroll
          for (int q = 0; q < 4; ++q)
            if ((u16)(b >> (16 * q))) atomicAdd(&bb[lai[e0 + 4 + q]], 0x10000u);
        }
      }
    }
  } else {
    {  // E: 4 fp32 per uint4
      const uint4* p = (const uint4*)((const float*)Se + (size_t)t0 * E_NO);
      const int wpr = E_NO / 4, total = nt * wpr;
      for (int w = tid; w < total; w += 256) {
        uint4 v = p[w];
        if (v.x | v.y | v.z | v.w) {
          int r = w / wpr, e0 = (w - r * wpr) * 4;
          u32* bb = &bins[r * SUB_NO];
          if (v.x) atomicAdd(&bb[lae[e0 + 0]], 1u);
          if (v.y) atomicAdd(&bb[lae[e0 + 1]], 1u);
          if (v.z) atomicAdd(&bb[lae[e0 + 2]], 1u);
          if (v.w) atomicAdd(&bb[lae[e0 + 3]], 1u);
        }
      }
    }
    {  // I
      const uint4* p = (const uint4*)((const float*)Si + (size_t)t0 * I_NO);
      const int wpr = I_NO / 4, total = nt * wpr;
      for (int w = tid; w < total; w += 256) {
        uint4 v = p[w];
        if (v.x | v.y | v.z | v.w) {
          int r = w / wpr, e0 = (w - r * wpr) * 4;
          u32* bb = &bins[r * SUB_NO];
          if (v.x) atomicAdd(&bb[lai[e0 + 0]], 0x10000u);
          if (v.y) atomicAdd(&bb[lai[e0 + 1]], 0x10000u);
          if (v.z) atomicAdd(&bb[lai[e0 + 2]], 0x10000u);
          if (v.w) atomicAdd(&bb[lai[e0 + 3]], 0x10000u);
        }
      }
    }
  }
  __syncthreads();
  for (int n = tid; n < nt * SUB_NO; n += 256)
    syn_pair[(size_t)t0 * SUB_NO + n] = bins[n];
}

// ---------------------------------------------------------------------------
// K2: conv + tree + epilogue reading packed counts. 128 threads = 128
// timesteps per block; tile = 328 rows x 20 u32 (26 KB) loaded via uint4.
// ---------------------------------------------------------------------------
#define K2_BT 128
#define K2_TR (K2_BT + T_NO)          // 328
#define K2_TW (K2_TR * SUB_NO / 4)    // 1640 uint4

__global__ __launch_bounds__(128) void k2_conv(
    const u32* __restrict__ probe,
    const u32* __restrict__ syn_pair, const float* __restrict__ kern4,
    const float* __restrict__ hist_s, const float* __restrict__ hist_ns,
    const void* __restrict__ Z, const void* __restrict__ Wsub_ns,
    const void* __restrict__ Wsub_s, const void* __restrict__ Vo,
    const void* __restrict__ Thns, const void* __restrict__ Ths,
    void* __restrict__ out) {
  const bool bf = (probe[0] != 0u);
  __shared__ uint4 tile4[K2_TW];
  __shared__ float ztile[K2_TR];
  __shared__ float lhs[T_NO], lhns[T_NO];
  __shared__ float ws2_l[SUB_NO], wns2_l[SUB_NO], ths_l[SUB_NO], thns_l[SUB_NO];
  const u32* tile = (const u32*)tile4;
  const int tid = threadIdx.x;
  const int t0 = blockIdx.x * K2_BT;

  const int base4 = (t0 - T_NO) * (SUB_NO / 4);  // uint4 index into syn_pair
  const uint4* sp4 = (const uint4*)syn_pair;
  for (int n = tid; n < K2_TW; n += 128) {
    int g = base4 + n;
    uint4 v = make_uint4(0u, 0u, 0u, 0u);
    if (g >= 0 && g < T_DATA * SUB_NO / 4) v = sp4[g];
    tile4[n] = v;
  }
  const int zbase = t0 - T_NO;
  for (int n = tid; n < K2_TR; n += 128) {
    int g = zbase + n;
    ztile[n] = (g >= 0 && g < T_DATA) ? ldx(Z, g, bf) : 0.f;
  }
  for (int n = tid; n < T_NO; n += 128) { lhs[n] = hist_s[n]; lhns[n] = hist_ns[n]; }
  if (tid < SUB_NO) {
    float w = ldx(Wsub_s, tid, bf);   ws2_l[tid]  = w * w;
    float wn = ldx(Wsub_ns, tid, bf); wns2_l[tid] = wn * wn;
    ths_l[tid]  = ldx(Ths, tid, bf);
    thns_l[tid] = ldx(Thns, tid, bf);
  }
  __syncthreads();

  float acc_ns[SUB_NO], acc_s[SUB_NO];
#pragma unroll
  for (int k = 0; k < SUB_NO; ++k) { acc_ns[k] = 0.f; acc_s[k] = 0.f; }
  float h_s = 0.f, h_ns = 0.f;
  const int lt = tid;

#pragma unroll 2
  for (int m = 0; m < T_NO; ++m) {
    const uint4* rp = &tile4[(lt + T_NO - m) * (SUB_NO / 4)];
    uint4 q0 = rp[0], q1 = rp[1], q2 = rp[2], q3 = rp[3], q4 = rp[4];
    u32 uu[SUB_NO] = {q0.x, q0.y, q0.z, q0.w, q1.x, q1.y, q1.z, q1.w,
                      q2.x, q2.y, q2.z, q2.w, q3.x, q3.y, q3.z, q3.w,
                      q4.x, q4.y, q4.z, q4.w};
    float zv = ztile[lt + T_NO - 1 - m];
    h_s  = fmaf(lhs[m],  zv, h_s);
    h_ns = fmaf(lhns[m], zv, h_ns);
    const float* kp = kern4 + m * (SUB_NO * 4);
#pragma unroll
    for (int k = 0; k < SUB_NO; ++k) {
      float ev = (float)(uu[k] & 0xFFFFu);  // exact integer counts
      float iv = (float)(uu[k] >> 16);
      acc_ns[k] = fmaf(kp[k * 4 + 0], ev, acc_ns[k]);
      acc_ns[k] = fmaf(kp[k * 4 + 1], iv, acc_ns[k]);
      acc_s[k]  = fmaf(kp[k * 4 + 2], ev, acc_s[k]);
      acc_s[k]  = fmaf(kp[k * 4 + 3], iv, acc_s[k]);
    }
  }

  // tree recursion (binary tree: children of k are 2k+1, 2k+2)
  float so[SUB_NO], no[SUB_NO];
#pragma unroll
  for (int k = SUB_NO - 1; k >= 1; --k) {
    float as_ = acc_s[k] + ths_l[k];
    float an_ = acc_ns[k] + thns_l[k];
    const int c1 = 2 * k + 1, c2 = 2 * k + 2;
    if (c1 < SUB_NO) { as_ += ws2_l[c1] * so[c1]; an_ += wns2_l[c1] * no[c1]; }
    if (c2 < SUB_NO) { as_ += ws2_l[c2] * so[c2]; an_ += wns2_l[c2] * no[c2]; }
    so[k] = tanhf(as_);
    no[k] = tanhf(an_);
  }
  float zs = h_s + acc_s[0] + ths_l[0] + ws2_l[1] * so[1] + ws2_l[2] * so[2];
  float zn = h_ns + acc_ns[0] + thns_l[0] + wns2_l[1] * no[1] + wns2_l[2] * no[2];
  float fZ = 1.f / (1.f + expf(-zs));
  float fV = tanhf(zn) * wns2_l[0] + ldx(Vo, 0, bf);

  const int t = t0 + lt;
  if (t < T_DATA) {
    stx(out, t, fV, bf);
    stx(out, T_DATA + t, fZ, bf);
  }
}

// ---------------------------------------------------------------------------
// Fallback fused kernel (used only if ws_size can't hold syn_pair).
// ---------------------------------------------------------------------------
#define KF_BT 256
#define KF_TR (KF_BT + T_NO)  // 456
__global__ __launch_bounds__(256) void k2_fused(
    const u32* __restrict__ probe,
    const void* __restrict__ Se, const void* __restrict__ Si,
    const float* __restrict__ kern4,
    const float* __restrict__ hist_s, const float* __restrict__ hist_ns,
    const int* __restrict__ ae, const int* __restrict__ ai,
    const void* __restrict__ Z, const void* __restrict__ Wsub_ns,
    const void* __restrict__ Wsub_s, const void* __restrict__ Vo,
    const void* __restrict__ Thns, const void* __restrict__ Ths,
    void* __restrict__ out) {
  const bool bf = (probe[0] != 0u);
  __shared__ u32 tile[KF_TR * SUB_NO];
  __shared__ float ztile[KF_TR];
  __shared__ int lae[E_NO];
  __shared__ int lai[I_NO];
  __shared__ float ws2_l[SUB_NO], wns2_l[SUB_NO], ths_l[SUB_NO], thns_l[SUB_NO];
  const int tid = threadIdx.x;
  const int t0 = blockIdx.x * KF_BT;

  for (int n = tid; n < KF_TR * SUB_NO; n += 256) tile[n] = 0u;
  for (int n = tid; n < E_NO; n += 256) lae[n] = ae[n];
  for (int n = tid; n < I_NO; n += 256) lai[n] = ai[n];
  const int zbase = t0 - T_NO;
  for (int n = tid; n < KF_TR; n += 256) {
    int g = zbase + n;
    ztile[n] = (g >= 0 && g < T_DATA) ? ldx(Z, g, bf) : 0.f;
  }
  if (tid < SUB_NO) {
    float w = ldx(Wsub_s, tid, bf);   ws2_l[tid]  = w * w;
    float wn = ldx(Wsub_ns, tid, bf); wns2_l[tid] = wn * wn;
    ths_l[tid]  = ldx(Ths, tid, bf);
    thns_l[tid] = ldx(Thns, tid, bf);
  }
  __syncthreads();

  const int row_lo = max(t0 - T_NO, 0);
  const int row_hi = min(t0 + KF_BT, T_DATA);
  const int nrows = row_hi - row_lo;
  const int lrow0 = row_lo - (t0 - T_NO);

  if (bf) {
    const u64* p4 = (const u64*)((const u16*)Se + (size_t)row_lo * E_NO);
    int total = nrows * (E_NO / 4);
    for (int p = tid; p < total; p += 256) {
      u64 u = p4[p];
      if (u) {
        int r = p / (E_NO / 4), e0 = (p - r * (E_NO / 4)) * 4;
        u32* base = &tile[(lrow0 + r) * SUB_NO];
#pragma unroll
        for (int q = 0; q < 4; ++q)
          if ((u16)(u >> (16 * q))) atomicAdd(&base[lae[e0 + q]], 1u);
      }
    }
    const u64* p4i = (const u64*)((const u16*)Si + (size_t)row_lo * I_NO);
    total = nrows * (I_NO / 4);
    for (int p = tid; p < total; p += 256) {
      u64 u = p4i[p];
      if (u) {
        int r = p / (I_NO / 4), e0 = (p - r * (I_NO / 4)) * 4;
        u32* base = &tile[(lrow0 + r) * SUB_NO];
#pragma unroll
        for (int q = 0; q < 4; ++q)
          if ((u16)(u >> (16 * q))) atomicAdd(&base[lai[e0 + q]], 0x10000u);
      }
    }
  } else {
    const uint4* p4 = (const uint4*)((const float*)Se + (size_t)row_lo * E_NO);
    int total = nrows * (E_NO / 4);
    for (int p = tid; p < total; p += 256) {
      uint4 u = p4[p];
      if (u.x | u.y | u.z | u.w) {
        int r = p / (E_NO / 4), e0 = (p - r * (E_NO / 4)) * 4;
        u32* base = &tile[(lrow0 + r) * SUB_NO];
        if (u.x) atomicAdd(&base[lae[e0 + 0]], 1u);
        if (u.y) atomicAdd(&base[lae[e0 + 1]], 1u);
        if (u.z) atomicAdd(&base[lae[e0 + 2]], 1u);
        if (u.w) atomicAdd(&base[lae[e0 + 3]], 1u);
      }
    }
    const uint4* p4i = (const uint4*)((const float*)Si + (size_t)row_lo * I_NO);
    total = nrows * (I_NO / 4);
    for (int p = tid; p < total; p += 256) {
      uint4 u = p4i[p];
      if (u.x | u.y | u.z | u.w) {
        int r = p / (I_NO / 4), e0 = (p - r * (I_NO / 4)) * 4;
        u32* base = &tile[(lrow0 + r) * SUB_NO];
        if (u.x) atomicAdd(&base[lai[e0 + 0]], 0x10000u);
        if (u.y) atomicAdd(&base[lai[e0 + 1]], 0x10000u);
        if (u.z) atomicAdd(&base[lai[e0 + 2]], 0x10000u);
        if (u.w) atomicAdd(&base[lai[e0 + 3]], 0x10000u);
      }
    }
  }
  __syncthreads();

  float acc_ns[SUB_NO], acc_s[SUB_NO];
#pragma unroll
  for (int k = 0; k < SUB_NO; ++k) { acc_ns[k] = 0.f; acc_s[k] = 0.f; }
  float h_s = 0.f, h_ns = 0.f;
  const int lt = tid;

#pragma unroll 2
  for (int m = 0; m < T_NO; ++m) {
    const uint4* rp = reinterpret_cast<const uint4*>(&tile[(lt + T_NO - m) * SUB_NO]);
    uint4 q0 = rp[0], q1 = rp[1], q2 = rp[2], q3 = rp[3], q4 = rp[4];
    u32 uu[SUB_NO] = {q0.x, q0.y, q0.z, q0.w, q1.x, q1.y, q1.z, q1.w,
                      q2.x, q2.y, q2.z, q2.w, q3.x, q3.y, q3.z, q3.w,
                      q4.x, q4.y, q4.z, q4.w};
    float zv = ztile[lt + T_NO - 1 - m];
    h_s  = fmaf(hist_s[m],  zv, h_s);
    h_ns = fmaf(hist_ns[m], zv, h_ns);
    const float* kp = kern4 + m * (SUB_NO * 4);
#pragma unroll
    for (int k = 0; k < SUB_NO; ++k) {
      float ev = (float)(uu[k] & 0xFFFFu);
      float iv = (float)(uu[k] >> 16);
      acc_ns[k] = fmaf(kp[k * 4 + 0], ev, acc_ns[k]);
      acc_ns[k] = fmaf(kp[k * 4 + 1], iv, acc_ns[k]);
      acc_s[k]  = fmaf(kp[k * 4 + 2], ev, acc_s[k]);
      acc_s[k]  = fmaf(kp[k * 4 + 3], iv, acc_s[k]);
    }
  }

  float so[SUB_NO], no[SUB_NO];
#pragma unroll
  for (int k = SUB_NO - 1; k >= 1; --k) {
    float as_ = acc_s[k] + ths_l[k];
    float an_ = acc_ns[k] + thns_l[k];
    const int c1 = 2 * k + 1, c2 = 2 * k + 2;
    if (c1 < SUB_NO) { as_ += ws2_l[c1] * so[c1]; an_ += wns2_l[c1] * no[c1]; }
    if (c2 < SUB_NO) { as_ += ws2_l[c2] * so[c2]; an_ += wns2_l[c2] * no[c2]; }
    so[k] = tanhf(as_);
    no[k] = tanhf(an_);
  }
  float zs = h_s + acc_s[0] + ths_l[0] + ws2_l[1] * so[1] + ws2_l[2] * so[2];
  float zn = h_ns + acc_ns[0] + thns_l[0] + wns2_l[1] * no[1] + wns2_l[2] * no[2];
  float fZ = 1.f / (1.f + expf(-zs));
  float fV = tanhf(zn) * wns2_l[0] + ldx(Vo, 0, bf);

  const int t = t0 + lt;
  if (t < T_DATA) {
    stx(out, t, fV, bf);
    stx(out, T_DATA + t, fZ, bf);
  }
}

// ---------------------------------------------------------------------------
extern "C" void kernel_launch(void* const* d_in, const int* in_sizes, int n_in,
                              void* d_out, int out_size, void* d_ws, size_t ws_size,
                              hipStream_t stream) {
  const void* Se      = d_in[0];
  const void* Si      = d_in[1];
  const void* Z       = d_in[2];
  const u32*  probe   = (const u32*)d_in[3];  // C_den dword0: 0 -> fp32, else bf16
  const void* Cse     = d_in[4];
  const void* Csi     = d_in[5];
  const void* Wns     = d_in[6];
  const void* Ws_     = d_in[7];
  const void* Wsub_ns = d_in[8];
  const void* Wsub_s  = d_in[9];
  const void* Vo      = d_in[10];
  const void* Thns    = d_in[11];
  const void* Ths     = d_in[12];
  const void* hsw     = d_in[13];
  const void* hnsw    = d_in[14];

  float* wsf      = (float*)d_ws;
  float* kern4    = wsf;                      // 16000 f
  float* hist_s   = wsf + 16000;              // 200 f
  float* hist_ns  = wsf + 16200;              // 200 f
  int*   ae       = (int*)(wsf + 16400);      // 800 i
  int*   ai       = (int*)(wsf + 17200);      // 200 i
  u32*   syn_pair = (u32*)(wsf + 17408);      // 2,000,000 u32 (16B-aligned)

  const size_t need = (size_t)17408 * 4 + (size_t)T_DATA * SUB_NO * 4;  // 8,069,632 B

  hipLaunchKernelGGL(k0_prep, dim3(K0_BLOCKS), dim3(256), 0, stream,
                     probe, Wns, Ws_, hsw, hnsw, Cse, Csi,
                     kern4, hist_s, hist_ns, ae, ai, d_out);
  if (ws_size >= need) {
    hipLaunchKernelGGL(k1_agg, dim3((T_DATA + K1_BT - 1) / K1_BT), dim3(256), 0, stream,
                       probe, Se, Si, ae, ai, syn_pair);
    hipLaunchKernelGGL(k2_conv, dim3((T_DATA + K2_BT - 1) / K2_BT), dim3(128), 0, stream,
                       probe, syn_pair, kern4, hist_s, hist_ns, Z,
                       Wsub_ns, Wsub_s, Vo, Thns, Ths, d_out);
  } else {
    hipLaunchKernelGGL(k2_fused, dim3((T_DATA + KF_BT - 1) / KF_BT), dim3(256), 0, stream,
                       probe, Se, Si, kern4, hist_s, hist_ns, ae, ai, Z,
                       Wsub_ns, Wsub_s, Vo, Thns, Ths, d_out);
  }
}

// Round 5
// 673.235 us; speedup vs baseline: 1.3123x; 1.0342x over previous
//
#include <hip/hip_runtime.h>
#include <hip/hip_bf16.h>
#include <math.h>

#define SUB_NO 20
#define T_NO   200
#define BASIS_NO 19
#define T_DATA 100000
#define E_NO   800
#define I_NO   200

using u16 = unsigned short;
using u32 = unsigned int;
using u64 = unsigned long long;

__device__ __forceinline__ float bf2f(u16 h) {
  return __builtin_bit_cast(float, (u32)h << 16);
}
__device__ __forceinline__ u16 f2bf(float f) {
  u32 u = __builtin_bit_cast(u32, f);
  u += 0x7FFFu + ((u >> 16) & 1u);  // RNE
  return (u16)(u >> 16);
}
// dtype-polymorphic load/store: bf==true -> bf16, else fp32
__device__ __forceinline__ float ldx(const void* p, int i, bool bf) {
  return bf ? bf2f(((const u16*)p)[i]) : ((const float*)p)[i];
}
__device__ __forceinline__ void stx(void* p, int i, float v, bool bf) {
  if (bf) ((u16*)p)[i] = f2bf(v); else ((float*)p)[i] = v;
}

// ---------------------------------------------------------------------------
// K0: multi-block. cos basis -> conv kernels (fp32 ws, [m][k][4]), hist
// kernels, out_filters, assignment tables.
// ---------------------------------------------------------------------------
#define K0_BLOCKS 21
__global__ __launch_bounds__(256) void k0_prep(
    const u32* __restrict__ probe,  // C_den dword0: 0 -> fp32, else bf16
    const void* __restrict__ Wns, const void* __restrict__ Ws,
    const void* __restrict__ hsw, const void* __restrict__ hnsw,
    const void* __restrict__ Cse, const void* __restrict__ Csi,
    float* __restrict__ kern4, float* __restrict__ hist_s,
    float* __restrict__ hist_ns, int* __restrict__ ae, int* __restrict__ ai,
    void* __restrict__ out) {
  const bool bf = (probe[0] != 0u);
  __shared__ float cb[BASIS_NO * T_NO];
  const int tid = threadIdx.x;
  constexpr float PI = 3.14159265358979323846f;
  for (int idx = tid; idx < BASIS_NO * T_NO; idx += 256) {
    int b = idx / T_NO, j = idx - b * T_NO;
    float phi = 0.5f * PI * (float)b;
    float raw = 5.0f * logf((float)j + 1.0f);
    float v = 0.f;
    if (raw >= phi - PI && raw <= phi + PI) v = 0.5f * cosf(raw - phi) + 0.5f;
    cb[idx] = v;
  }
  __syncthreads();
  const int fbase = 2 * T_DATA;
  for (int gid = blockIdx.x * 256 + tid; gid < 5200; gid += K0_BLOCKS * 256) {
    if (gid < 4000) {
      int k = gid / T_NO, j = gid - k * T_NO;
      float e_ns = 0.f, i_ns = 0.f, e_s = 0.f, i_s = 0.f;
#pragma unroll
      for (int b = 0; b < BASIS_NO; ++b) {
        float c = cb[b * T_NO + j];
        e_ns = fmaf(ldx(Wns, (k * BASIS_NO + b) * 2 + 0, bf), c, e_ns);
        i_ns = fmaf(ldx(Wns, (k * BASIS_NO + b) * 2 + 1, bf), c, i_ns);
        e_s  = fmaf(ldx(Ws,  (k * BASIS_NO + b) * 2 + 0, bf), c, e_s);
        i_s  = fmaf(ldx(Ws,  (k * BASIS_NO + b) * 2 + 1, bf), c, i_s);
      }
      float* kp = kern4 + (j * SUB_NO + k) * 4;
      kp[0] = e_ns; kp[1] = i_ns; kp[2] = e_s; kp[3] = i_s;
      stx(out, fbase + (0 * SUB_NO + k) * T_NO + j, e_ns, bf);
      stx(out, fbase + (1 * SUB_NO + k) * T_NO + j, i_ns, bf);
      stx(out, fbase + (2 * SUB_NO + k) * T_NO + j, e_s,  bf);
      stx(out, fbase + (3 * SUB_NO + k) * T_NO + j, i_s,  bf);
    } else if (gid < 4200) {
      int j = gid - 4000;
      float hs = 0.f, hns = 0.f;
#pragma unroll
      for (int b = 0; b < BASIS_NO; ++b) {
        float c = cb[b * T_NO + j];
        hs  = fmaf(ldx(hsw,  b, bf), c, hs);
        hns = fmaf(ldx(hnsw, b, bf), c, hns);
      }
      hist_s[j] = hs; hist_ns[j] = hns;
      stx(out, fbase + 80 * T_NO + j, hns, bf);
      stx(out, fbase + 81 * T_NO + j, hs,  bf);
    } else if (gid < 5000) {
      int e = gid - 4200;
      int a = 0;
      for (int k = 0; k < SUB_NO; ++k) if (ldx(Cse, k * E_NO + e, bf) != 0.f) a = k;
      ae[e] = a;
    } else {
      int e = gid - 5000;
      int a = 0;
      for (int k = 0; k < SUB_NO; ++k) if (ldx(Csi, k * I_NO + e, bf) != 0.f) a = k;
      ai[e] = a;
    }
  }
}

// ---------------------------------------------------------------------------
// K1: stream spikes once, unroll-4 independent loads for MLP, bin via integer
// LDS atomics (exact), write packed bf16 pair (e | i<<16) per (t,k).
// Counts << 256 so bf16 is exact.
// ---------------------------------------------------------------------------
#define K1_BT 64
__device__ __forceinline__ void proc8(uint4 v, int w, int wpr, u32* bins,
                                      const int* tbl, u32 inc) {
  u64 a = ((u64)v.y << 32) | v.x;
  u64 b = ((u64)v.w << 32) | v.z;
  if (a | b) {
    int r = w / wpr, e0 = (w - r * wpr) * 8;
    u32* bb = &bins[r * SUB_NO];
#pragma unroll
    for (int q = 0; q < 4; ++q)
      if ((u16)(a >> (16 * q))) atomicAdd(&bb[tbl[e0 + q]], inc);
#pragma unroll
    for (int q = 0; q < 4; ++q)
      if ((u16)(b >> (16 * q))) atomicAdd(&bb[tbl[e0 + 4 + q]], inc);
  }
}
__device__ __forceinline__ void proc4(uint4 v, int w, int wpr, u32* bins,
                                      const int* tbl, u32 inc) {
  if (v.x | v.y | v.z | v.w) {
    int r = w / wpr, e0 = (w - r * wpr) * 4;
    u32* bb = &bins[r * SUB_NO];
    if (v.x) atomicAdd(&bb[tbl[e0 + 0]], inc);
    if (v.y) atomicAdd(&bb[tbl[e0 + 1]], inc);
    if (v.z) atomicAdd(&bb[tbl[e0 + 2]], inc);
    if (v.w) atomicAdd(&bb[tbl[e0 + 3]], inc);
  }
}

__global__ __launch_bounds__(256) void k1_agg(
    const u32* __restrict__ probe,
    const void* __restrict__ Se, const void* __restrict__ Si,
    const int* __restrict__ ae, const int* __restrict__ ai,
    u32* __restrict__ syn_pair) {
  const bool bf = (probe[0] != 0u);
  __shared__ u32 bins[K1_BT * SUB_NO];
  __shared__ int lae[E_NO];
  __shared__ int lai[I_NO];
  const int tid = threadIdx.x;
  const int t0 = blockIdx.x * K1_BT;
  if (t0 >= T_DATA) return;
  const int nt = min(K1_BT, T_DATA - t0);
  for (int n = tid; n < K1_BT * SUB_NO; n += 256) bins[n] = 0u;
  for (int n = tid; n < E_NO; n += 256) lae[n] = ae[n];
  for (int n = tid; n < I_NO; n += 256) lai[n] = ai[n];
  __syncthreads();
  const uint4 z4 = make_uint4(0u, 0u, 0u, 0u);

  if (bf) {
    {
      const uint4* p = (const uint4*)((const u16*)Se + (size_t)t0 * E_NO);
      const int wpr = E_NO / 8, total = nt * wpr;
      for (int w = tid; w < total; w += 1024) {
        int w1 = w + 256, w2 = w + 512, w3 = w + 768;
        uint4 v0 = p[w];
        uint4 v1 = (w1 < total) ? p[w1] : z4;
        uint4 v2 = (w2 < total) ? p[w2] : z4;
        uint4 v3 = (w3 < total) ? p[w3] : z4;
        proc8(v0, w, wpr, bins, lae, 1u);
        proc8(v1, w1, wpr, bins, lae, 1u);
        proc8(v2, w2, wpr, bins, lae, 1u);
        proc8(v3, w3, wpr, bins, lae, 1u);
      }
    }
    {
      const uint4* p = (const uint4*)((const u16*)Si + (size_t)t0 * I_NO);
      const int wpr = I_NO / 8, total = nt * wpr;
      for (int w = tid; w < total; w += 1024) {
        int w1 = w + 256, w2 = w + 512, w3 = w + 768;
        uint4 v0 = p[w];
        uint4 v1 = (w1 < total) ? p[w1] : z4;
        uint4 v2 = (w2 < total) ? p[w2] : z4;
        uint4 v3 = (w3 < total) ? p[w3] : z4;
        proc8(v0, w, wpr, bins, lai, 0x10000u);
        proc8(v1, w1, wpr, bins, lai, 0x10000u);
        proc8(v2, w2, wpr, bins, lai, 0x10000u);
        proc8(v3, w3, wpr, bins, lai, 0x10000u);
      }
    }
  } else {
    {
      const uint4* p = (const uint4*)((const float*)Se + (size_t)t0 * E_NO);
      const int wpr = E_NO / 4, total = nt * wpr;
      for (int w = tid; w < total; w += 1024) {
        int w1 = w + 256, w2 = w + 512, w3 = w + 768;
        uint4 v0 = p[w];
        uint4 v1 = (w1 < total) ? p[w1] : z4;
        uint4 v2 = (w2 < total) ? p[w2] : z4;
        uint4 v3 = (w3 < total) ? p[w3] : z4;
        proc4(v0, w, wpr, bins, lae, 1u);
        proc4(v1, w1, wpr, bins, lae, 1u);
        proc4(v2, w2, wpr, bins, lae, 1u);
        proc4(v3, w3, wpr, bins, lae, 1u);
      }
    }
    {
      const uint4* p = (const uint4*)((const float*)Si + (size_t)t0 * I_NO);
      const int wpr = I_NO / 4, total = nt * wpr;
      for (int w = tid; w < total; w += 1024) {
        int w1 = w + 256, w2 = w + 512, w3 = w + 768;
        uint4 v0 = p[w];
        uint4 v1 = (w1 < total) ? p[w1] : z4;
        uint4 v2 = (w2 < total) ? p[w2] : z4;
        uint4 v3 = (w3 < total) ? p[w3] : z4;
        proc4(v0, w, wpr, bins, lai, 0x10000u);
        proc4(v1, w1, wpr, bins, lai, 0x10000u);
        proc4(v2, w2, wpr, bins, lai, 0x10000u);
        proc4(v3, w3, wpr, bins, lai, 0x10000u);
      }
    }
  }
  __syncthreads();
  // pack integer counts -> bf16 pair (exact for counts < 257)
  for (int n = tid; n < nt * SUB_NO; n += 256) {
    u32 c = bins[n];
    u32 pe = (u32)f2bf((float)(c & 0xFFFFu));
    u32 pi = (u32)f2bf((float)(c >> 16));
    syn_pair[(size_t)t0 * SUB_NO + n] = pe | (pi << 16);
  }
}

// ---------------------------------------------------------------------------
// K2: conv + tree + epilogue. Tile holds packed bf16 pairs; unpack is
// 1 shift + 1 and per subunit. Stride-20-word rows: 8 lanes x b128 cover all
// 32 banks (conflict-free).
// ---------------------------------------------------------------------------
#define K2_BT 128
#define K2_TR (K2_BT + T_NO)          // 328
#define K2_TW (K2_TR * SUB_NO / 4)    // 1640 uint4

__global__ __launch_bounds__(128) void k2_conv(
    const u32* __restrict__ probe,
    const u32* __restrict__ syn_pair, const float* __restrict__ kern4,
    const float* __restrict__ hist_s, const float* __restrict__ hist_ns,
    const void* __restrict__ Z, const void* __restrict__ Wsub_ns,
    const void* __restrict__ Wsub_s, const void* __restrict__ Vo,
    const void* __restrict__ Thns, const void* __restrict__ Ths,
    void* __restrict__ out) {
  const bool bf = (probe[0] != 0u);
  __shared__ uint4 tile4[K2_TW];
  __shared__ float ztile[K2_TR];
  __shared__ float lhs[T_NO], lhns[T_NO];
  __shared__ float ws2_l[SUB_NO], wns2_l[SUB_NO], ths_l[SUB_NO], thns_l[SUB_NO];
  const int tid = threadIdx.x;
  const int t0 = blockIdx.x * K2_BT;

  const int base4 = (t0 - T_NO) * (SUB_NO / 4);
  const uint4* sp4 = (const uint4*)syn_pair;
  for (int n = tid; n < K2_TW; n += 128) {
    int g = base4 + n;
    uint4 v = make_uint4(0u, 0u, 0u, 0u);
    if (g >= 0 && g < T_DATA * SUB_NO / 4) v = sp4[g];
    tile4[n] = v;
  }
  const int zbase = t0 - T_NO;
  for (int n = tid; n < K2_TR; n += 128) {
    int g = zbase + n;
    ztile[n] = (g >= 0 && g < T_DATA) ? ldx(Z, g, bf) : 0.f;
  }
  for (int n = tid; n < T_NO; n += 128) { lhs[n] = hist_s[n]; lhns[n] = hist_ns[n]; }
  if (tid < SUB_NO) {
    float w = ldx(Wsub_s, tid, bf);   ws2_l[tid]  = w * w;
    float wn = ldx(Wsub_ns, tid, bf); wns2_l[tid] = wn * wn;
    ths_l[tid]  = ldx(Ths, tid, bf);
    thns_l[tid] = ldx(Thns, tid, bf);
  }
  __syncthreads();

  float acc_ns[SUB_NO], acc_s[SUB_NO];
#pragma unroll
  for (int k = 0; k < SUB_NO; ++k) { acc_ns[k] = 0.f; acc_s[k] = 0.f; }
  float h_s = 0.f, h_ns = 0.f;
  const int lt = tid;

#pragma unroll 2
  for (int m = 0; m < T_NO; ++m) {
    const uint4* rp = &tile4[(lt + T_NO - m) * (SUB_NO / 4)];
    uint4 q0 = rp[0], q1 = rp[1], q2 = rp[2], q3 = rp[3], q4 = rp[4];
    u32 uu[SUB_NO] = {q0.x, q0.y, q0.z, q0.w, q1.x, q1.y, q1.z, q1.w,
                      q2.x, q2.y, q2.z, q2.w, q3.x, q3.y, q3.z, q3.w,
                      q4.x, q4.y, q4.z, q4.w};
    float zv = ztile[lt + T_NO - 1 - m];
    h_s  = fmaf(lhs[m],  zv, h_s);
    h_ns = fmaf(lhns[m], zv, h_ns);
    const float* kp = kern4 + m * (SUB_NO * 4);
#pragma unroll
    for (int k = 0; k < SUB_NO; ++k) {
      float ev = __builtin_bit_cast(float, uu[k] << 16);
      float iv = __builtin_bit_cast(float, uu[k] & 0xFFFF0000u);
      acc_ns[k] = fmaf(kp[k * 4 + 0], ev, acc_ns[k]);
      acc_ns[k] = fmaf(kp[k * 4 + 1], iv, acc_ns[k]);
      acc_s[k]  = fmaf(kp[k * 4 + 2], ev, acc_s[k]);
      acc_s[k]  = fmaf(kp[k * 4 + 3], iv, acc_s[k]);
    }
  }

  // tree recursion (binary tree: children of k are 2k+1, 2k+2)
  float so[SUB_NO], no[SUB_NO];
#pragma unroll
  for (int k = SUB_NO - 1; k >= 1; --k) {
    float as_ = acc_s[k] + ths_l[k];
    float an_ = acc_ns[k] + thns_l[k];
    const int c1 = 2 * k + 1, c2 = 2 * k + 2;
    if (c1 < SUB_NO) { as_ += ws2_l[c1] * so[c1]; an_ += wns2_l[c1] * no[c1]; }
    if (c2 < SUB_NO) { as_ += ws2_l[c2] * so[c2]; an_ += wns2_l[c2] * no[c2]; }
    so[k] = tanhf(as_);
    no[k] = tanhf(an_);
  }
  float zs = h_s + acc_s[0] + ths_l[0] + ws2_l[1] * so[1] + ws2_l[2] * so[2];
  float zn = h_ns + acc_ns[0] + thns_l[0] + wns2_l[1] * no[1] + wns2_l[2] * no[2];
  float fZ = 1.f / (1.f + expf(-zs));
  float fV = tanhf(zn) * wns2_l[0] + ldx(Vo, 0, bf);

  const int t = t0 + lt;
  if (t < T_DATA) {
    stx(out, t, fV, bf);
    stx(out, T_DATA + t, fZ, bf);
  }
}

// ---------------------------------------------------------------------------
// Fallback fused kernel (only if ws_size can't hold syn_pair).
// ---------------------------------------------------------------------------
#define KF_BT 256
#define KF_TR (KF_BT + T_NO)  // 456
__global__ __launch_bounds__(256) void k2_fused(
    const u32* __restrict__ probe,
    const void* __restrict__ Se, const void* __restrict__ Si,
    const float* __restrict__ kern4,
    const float* __restrict__ hist_s, const float* __restrict__ hist_ns,
    const int* __restrict__ ae, const int* __restrict__ ai,
    const void* __restrict__ Z, const void* __restrict__ Wsub_ns,
    const void* __restrict__ Wsub_s, const void* __restrict__ Vo,
    const void* __restrict__ Thns, const void* __restrict__ Ths,
    void* __restrict__ out) {
  const bool bf = (probe[0] != 0u);
  __shared__ u32 tile[KF_TR * SUB_NO];
  __shared__ float ztile[KF_TR];
  __shared__ int lae[E_NO];
  __shared__ int lai[I_NO];
  __shared__ float ws2_l[SUB_NO], wns2_l[SUB_NO], ths_l[SUB_NO], thns_l[SUB_NO];
  const int tid = threadIdx.x;
  const int t0 = blockIdx.x * KF_BT;

  for (int n = tid; n < KF_TR * SUB_NO; n += 256) tile[n] = 0u;
  for (int n = tid; n < E_NO; n += 256) lae[n] = ae[n];
  for (int n = tid; n < I_NO; n += 256) lai[n] = ai[n];
  const int zbase = t0 - T_NO;
  for (int n = tid; n < KF_TR; n += 256) {
    int g = zbase + n;
    ztile[n] = (g >= 0 && g < T_DATA) ? ldx(Z, g, bf) : 0.f;
  }
  if (tid < SUB_NO) {
    float w = ldx(Wsub_s, tid, bf);   ws2_l[tid]  = w * w;
    float wn = ldx(Wsub_ns, tid, bf); wns2_l[tid] = wn * wn;
    ths_l[tid]  = ldx(Ths, tid, bf);
    thns_l[tid] = ldx(Thns, tid, bf);
  }
  __syncthreads();

  const int row_lo = max(t0 - T_NO, 0);
  const int row_hi = min(t0 + KF_BT, T_DATA);
  const int nrows = row_hi - row_lo;
  const int lrow0 = row_lo - (t0 - T_NO);

  if (bf) {
    const u64* p4 = (const u64*)((const u16*)Se + (size_t)row_lo * E_NO);
    int total = nrows * (E_NO / 4);
    for (int p = tid; p < total; p += 256) {
      u64 u = p4[p];
      if (u) {
        int r = p / (E_NO / 4), e0 = (p - r * (E_NO / 4)) * 4;
        u32* base = &tile[(lrow0 + r) * SUB_NO];
#pragma unroll
        for (int q = 0; q < 4; ++q)
          if ((u16)(u >> (16 * q))) atomicAdd(&base[lae[e0 + q]], 1u);
      }
    }
    const u64* p4i = (const u64*)((const u16*)Si + (size_t)row_lo * I_NO);
    total = nrows * (I_NO / 4);
    for (int p = tid; p < total; p += 256) {
      u64 u = p4i[p];
      if (u) {
        int r = p / (I_NO / 4), e0 = (p - r * (I_NO / 4)) * 4;
        u32* base = &tile[(lrow0 + r) * SUB_NO];
#pragma unroll
        for (int q = 0; q < 4; ++q)
          if ((u16)(u >> (16 * q))) atomicAdd(&base[lai[e0 + q]], 0x10000u);
      }
    }
  } else {
    const uint4* p4 = (const uint4*)((const float*)Se + (size_t)row_lo * E_NO);
    int total = nrows * (E_NO / 4);
    for (int p = tid; p < total; p += 256) {
      uint4 u = p4[p];
      if (u.x | u.y | u.z | u.w) {
        int r = p / (E_NO / 4), e0 = (p - r * (E_NO / 4)) * 4;
        u32* base = &tile[(lrow0 + r) * SUB_NO];
        if (u.x) atomicAdd(&base[lae[e0 + 0]], 1u);
        if (u.y) atomicAdd(&base[lae[e0 + 1]], 1u);
        if (u.z) atomicAdd(&base[lae[e0 + 2]], 1u);
        if (u.w) atomicAdd(&base[lae[e0 + 3]], 1u);
      }
    }
    const uint4* p4i = (const uint4*)((const float*)Si + (size_t)row_lo * I_NO);
    total = nrows * (I_NO / 4);
    for (int p = tid; p < total; p += 256) {
      uint4 u = p4i[p];
      if (u.x | u.y | u.z | u.w) {
        int r = p / (I_NO / 4), e0 = (p - r * (I_NO / 4)) * 4;
        u32* base = &tile[(lrow0 + r) * SUB_NO];
        if (u.x) atomicAdd(&base[lai[e0 + 0]], 0x10000u);
        if (u.y) atomicAdd(&base[lai[e0 + 1]], 0x10000u);
        if (u.z) atomicAdd(&base[lai[e0 + 2]], 0x10000u);
        if (u.w) atomicAdd(&base[lai[e0 + 3]], 0x10000u);
      }
    }
  }
  __syncthreads();

  float acc_ns[SUB_NO], acc_s[SUB_NO];
#pragma unroll
  for (int k = 0; k < SUB_NO; ++k) { acc_ns[k] = 0.f; acc_s[k] = 0.f; }
  float h_s = 0.f, h_ns = 0.f;
  const int lt = tid;

#pragma unroll 2
  for (int m = 0; m < T_NO; ++m) {
    const uint4* rp = reinterpret_cast<const uint4*>(&tile[(lt + T_NO - m) * SUB_NO]);
    uint4 q0 = rp[0], q1 = rp[1], q2 = rp[2], q3 = rp[3], q4 = rp[4];
    u32 uu[SUB_NO] = {q0.x, q0.y, q0.z, q0.w, q1.x, q1.y, q1.z, q1.w,
                      q2.x, q2.y, q2.z, q2.w, q3.x, q3.y, q3.z, q3.w,
                      q4.x, q4.y, q4.z, q4.w};
    float zv = ztile[lt + T_NO - 1 - m];
    h_s  = fmaf(hist_s[m],  zv, h_s);
    h_ns = fmaf(hist_ns[m], zv, h_ns);
    const float* kp = kern4 + m * (SUB_NO * 4);
#pragma unroll
    for (int k = 0; k < SUB_NO; ++k) {
      float ev = (float)(uu[k] & 0xFFFFu);
      float iv = (float)(uu[k] >> 16);
      acc_ns[k] = fmaf(kp[k * 4 + 0], ev, acc_ns[k]);
      acc_ns[k] = fmaf(kp[k * 4 + 1], iv, acc_ns[k]);
      acc_s[k]  = fmaf(kp[k * 4 + 2], ev, acc_s[k]);
      acc_s[k]  = fmaf(kp[k * 4 + 3], iv, acc_s[k]);
    }
  }

  float so[SUB_NO], no[SUB_NO];
#pragma unroll
  for (int k = SUB_NO - 1; k >= 1; --k) {
    float as_ = acc_s[k] + ths_l[k];
    float an_ = acc_ns[k] + thns_l[k];
    const int c1 = 2 * k + 1, c2 = 2 * k + 2;
    if (c1 < SUB_NO) { as_ += ws2_l[c1] * so[c1]; an_ += wns2_l[c1] * no[c1]; }
    if (c2 < SUB_NO) { as_ += ws2_l[c2] * so[c2]; an_ += wns2_l[c2] * no[c2]; }
    so[k] = tanhf(as_);
    no[k] = tanhf(an_);
  }
  float zs = h_s + acc_s[0] + ths_l[0] + ws2_l[1] * so[1] + ws2_l[2] * so[2];
  float zn = h_ns + acc_ns[0] + thns_l[0] + wns2_l[1] * no[1] + wns2_l[2] * no[2];
  float fZ = 1.f / (1.f + expf(-zs));
  float fV = tanhf(zn) * wns2_l[0] + ldx(Vo, 0, bf);

  const int t = t0 + lt;
  if (t < T_DATA) {
    stx(out, t, fV, bf);
    stx(out, T_DATA + t, fZ, bf);
  }
}

// ---------------------------------------------------------------------------
extern "C" void kernel_launch(void* const* d_in, const int* in_sizes, int n_in,
                              void* d_out, int out_size, void* d_ws, size_t ws_size,
                              hipStream_t stream) {
  const void* Se      = d_in[0];
  const void* Si      = d_in[1];
  const void* Z       = d_in[2];
  const u32*  probe   = (const u32*)d_in[3];  // C_den dword0: 0 -> fp32, else bf16
  const void* Cse     = d_in[4];
  const void* Csi     = d_in[5];
  const void* Wns     = d_in[6];
  const void* Ws_     = d_in[7];
  const void* Wsub_ns = d_in[8];
  const void* Wsub_s  = d_in[9];
  const void* Vo      = d_in[10];
  const void* Thns    = d_in[11];
  const void* Ths     = d_in[12];
  const void* hsw     = d_in[13];
  const void* hnsw    = d_in[14];

  float* wsf      = (float*)d_ws;
  float* kern4    = wsf;                      // 16000 f
  float* hist_s   = wsf + 16000;              // 200 f
  float* hist_ns  = wsf + 16200;              // 200 f
  int*   ae       = (int*)(wsf + 16400);      // 800 i
  int*   ai       = (int*)(wsf + 17200);      // 200 i
  u32*   syn_pair = (u32*)(wsf + 17408);      // 2,000,000 u32 (16B-aligned)

  const size_t need = (size_t)17408 * 4 + (size_t)T_DATA * SUB_NO * 4;  // ~8.07 MB

  hipLaunchKernelGGL(k0_prep, dim3(K0_BLOCKS), dim3(256), 0, stream,
                     probe, Wns, Ws_, hsw, hnsw, Cse, Csi,
                     kern4, hist_s, hist_ns, ae, ai, d_out);
  if (ws_size >= need) {
    hipLaunchKernelGGL(k1_agg, dim3((T_DATA + K1_BT - 1) / K1_BT), dim3(256), 0, stream,
                       probe, Se, Si, ae, ai, syn_pair);
    hipLaunchKernelGGL(k2_conv, dim3((T_DATA + K2_BT - 1) / K2_BT), dim3(128), 0, stream,
                       probe, syn_pair, kern4, hist_s, hist_ns, Z,
                       Wsub_ns, Wsub_s, Vo, Thns, Ths, d_out);
  } else {
    hipLaunchKernelGGL(k2_fused, dim3((T_DATA + KF_BT - 1) / KF_BT), dim3(256), 0, stream,
                       probe, Se, Si, kern4, hist_s, hist_ns, ae, ai, Z,
                       Wsub_ns, Wsub_s, Vo, Thns, Ths, d_out);
  }
}